// Round 4
// baseline (502.529 us; speedup 1.0000x reference)
//
#include <hip/hip_runtime.h>
#include <math.h>

// Problem constants
#define NF 5
#define NB 8
#define NC 64
#define HW 16384
#define NK 320               // NF*NC
#define FSTRIDE (NB*NC*HW)   // elements per frame = 8388608

// ws layout (floats)
#define EN_FLOATS    (NB*NC*8)   // 4096: per (b,c): E0..E3, N0..N3
#define ALPHA_FLOATS (NB*NK)     // 2560
#define OT_STRIDE 65             // LDS row stride -> bank (j+lane)%32, conflict-free

// --- preprocessor repetition: named scalars so NO alloca exists to demote ---
#define R32L(M) M(0) M(1) M(2) M(3) M(4) M(5) M(6) M(7) M(8) M(9) M(10) M(11) \
  M(12) M(13) M(14) M(15) M(16) M(17) M(18) M(19) M(20) M(21) M(22) M(23) \
  M(24) M(25) M(26) M(27) M(28) M(29) M(30) M(31)
#define R32H(M) M(32) M(33) M(34) M(35) M(36) M(37) M(38) M(39) M(40) M(41) \
  M(42) M(43) M(44) M(45) M(46) M(47) M(48) M(49) M(50) M(51) M(52) M(53) \
  M(54) M(55) M(56) M(57) M(58) M(59) M(60) M(61) M(62) M(63)
#define R64(M) R32L(M) R32H(M)

// ---------------- k0: transpose origin_w [64][320] -> Wt [320][64] ----------------
__global__ void k0_wt(const float* __restrict__ W, float* __restrict__ Wt){
    int idx = blockIdx.x*256 + threadIdx.x;
    if (idx < NC*NK){
        int c = idx / NK;
        int k = idx - c*NK;
        Wt[k*NC + c] = W[idx];   // Wt row k = 64 contiguous c -> s_load_dwordx16 friendly
    }
}

// ---------------- k1: fused GEMM + E/N reduction, wave-independent ----------------
// Wave w owns tile t = blk*4+w: 64 spatial positions, lane = s.
// Phase A: o[c] = bias[c] + sum_k Wt[k][c]*X[k,s] into 64 NAMED scalar floats
//   (rounds 2-3: float acc[64] alloca was demoted to scratch -> VGPR=64,
//    WRITE_SIZE=32MB spill traffic, VALUBusy 16%. Named scalars are SSA values;
//    there is no alloca for PromoteAlloca to refuse.)
//   W row k is wave-uniform -> s_load; X load is 1 dword/lane coalesced.
// Phase B (per c-half): transpose o via per-wave LDS, lane=(c_local, s_half),
//   re-read X rows, accumulate E/N in named scalars, shfl-combine, atomicAdd.
__global__ __launch_bounds__(256, 4) void k1_fused(
    const float* __restrict__ inp, const float* __restrict__ Wt,
    const float* __restrict__ bias, float* __restrict__ EN)
{
    __shared__ float oT[4][32*OT_STRIDE];   // per-wave private buffers, 33.3 KB

    const int tid  = threadIdx.x;
    const int w    = tid >> 6;
    const int lane = tid & 63;
    const int t    = blockIdx.x*4 + w;      // 0..2047
    const int b    = t >> 8;                // 256 tiles per batch
    const int s0   = (t & 255) << 6;        // tile base spatial
    float* obuf = oT[w];

    // ---- Phase A: 64 named accumulators ----
#define DECL_ACC(i) float a##i = bias[i];
    R64(DECL_ACC)
#undef DECL_ACC

#pragma unroll 1
    for (int f=0; f<NF; ++f){
        const float* fb = inp + (size_t)(f*NB + b)*NC*HW + s0 + lane;
        const float* wb = Wt + f*64*NC;
#pragma unroll 4
        for (int k=0; k<64; ++k){
            float x = fb[(size_t)k*HW];              // coalesced 256B/wave
            const float* wk = wb + k*NC;             // uniform -> s_load_dwordx16
#define FMA_A(i) a##i = fmaf(wk[i], x, a##i);
            R64(FMA_A)
#undef FMA_A
        }
    }

    // ---- Phase B ----
    const int cl = lane & 31;       // c within half
    const int sh = lane >> 5;       // s-half
    float* enb = EN + (size_t)b*NC*8;

    { // ---- half 0: channels 0..31 ----
#define ST0(i) obuf[(i)*OT_STRIDE + lane] = a##i;
        R32L(ST0)
#undef ST0
        const float* orow = obuf + cl*OT_STRIDE + sh*32;
        const float* base = inp + ((size_t)b*NC + cl)*HW + s0 + sh*32;
        float e0=0,e1=0,e2=0,e3=0,n0=0,n1=0,n2=0,n3=0;
#pragma unroll
        for (int j4=0; j4<8; ++j4){
            float4 ov = *reinterpret_cast<const float4*>(orow + j4*4);       // ds_read_b128
            float4 x4 = *reinterpret_cast<const float4*>(base + (size_t)4*FSTRIDE + j4*4);
#define EN_STEP(i, E, N) { \
            float4 xi = *reinterpret_cast<const float4*>(base + (size_t)(i)*FSTRIDE + j4*4); \
            float d0=x4.x-xi.x, d1=x4.y-xi.y, d2=x4.z-xi.z, d3=x4.w-xi.w; \
            N = fmaf(d0,d0, fmaf(d1,d1, fmaf(d2,d2, fmaf(d3,d3, N)))); \
            E = fmaf(ov.x,d0, fmaf(ov.y,d1, fmaf(ov.z,d2, fmaf(ov.w,d3, E)))); }
            EN_STEP(0, e0, n0) EN_STEP(1, e1, n1) EN_STEP(2, e2, n2) EN_STEP(3, e3, n3)
        }
        e0 += __shfl_xor(e0,32,64); e1 += __shfl_xor(e1,32,64);
        e2 += __shfl_xor(e2,32,64); e3 += __shfl_xor(e3,32,64);
        n0 += __shfl_xor(n0,32,64); n1 += __shfl_xor(n1,32,64);
        n2 += __shfl_xor(n2,32,64); n3 += __shfl_xor(n3,32,64);
        if (lane < 32){
            atomicAdd(&enb[cl*8+0], e0); atomicAdd(&enb[cl*8+1], e1);
            atomicAdd(&enb[cl*8+2], e2); atomicAdd(&enb[cl*8+3], e3);
            atomicAdd(&enb[cl*8+4], n0); atomicAdd(&enb[cl*8+5], n1);
            atomicAdd(&enb[cl*8+6], n2); atomicAdd(&enb[cl*8+7], n3);
        }
    }

    { // ---- half 1: channels 32..63 ----
#define ST1(i) obuf[((i)-32)*OT_STRIDE + lane] = a##i;
        R32H(ST1)
#undef ST1
        const float* orow = obuf + cl*OT_STRIDE + sh*32;
        const float* base = inp + ((size_t)b*NC + 32 + cl)*HW + s0 + sh*32;
        float e0=0,e1=0,e2=0,e3=0,n0=0,n1=0,n2=0,n3=0;
#pragma unroll
        for (int j4=0; j4<8; ++j4){
            float4 ov = *reinterpret_cast<const float4*>(orow + j4*4);
            float4 x4 = *reinterpret_cast<const float4*>(base + (size_t)4*FSTRIDE + j4*4);
            EN_STEP(0, e0, n0) EN_STEP(1, e1, n1) EN_STEP(2, e2, n2) EN_STEP(3, e3, n3)
#undef EN_STEP
        }
        e0 += __shfl_xor(e0,32,64); e1 += __shfl_xor(e1,32,64);
        e2 += __shfl_xor(e2,32,64); e3 += __shfl_xor(e3,32,64);
        n0 += __shfl_xor(n0,32,64); n1 += __shfl_xor(n1,32,64);
        n2 += __shfl_xor(n2,32,64); n3 += __shfl_xor(n3,32,64);
        if (lane < 32){
            int c = 32 + cl;
            atomicAdd(&enb[c*8+0], e0); atomicAdd(&enb[c*8+1], e1);
            atomicAdd(&enb[c*8+2], e2); atomicAdd(&enb[c*8+3], e3);
            atomicAdd(&enb[c*8+4], n0); atomicAdd(&enb[c*8+5], n1);
            atomicAdd(&enb[c*8+6], n2); atomicAdd(&enb[c*8+7], n3);
        }
    }
}

// ---------------- k2: finalize coef -> alpha ----------------
__global__ void k2_coef(const float* __restrict__ EN, const float* __restrict__ out_w,
                        float* __restrict__ alpha)
{
    int tid = threadIdx.x;          // 512 = NB*NC
    int b = tid >> 6, c = tid & 63;
    const float* e = EN + (b*NC + c)*8;
    float w1 = out_w[c], w2 = out_w[NC + c];
    float csum = 0.f;
#pragma unroll
    for (int i=0; i<4; ++i){
        float n = fmaxf(sqrtf(e[4+i]), 1e-12f);
        float coef = e[i] / (n*n);
        alpha[b*NK + i*NC + c] = -w1*coef;
        csum += coef;
    }
    alpha[b*NK + 4*NC + c] = w1*csum + w2;
}

// ---------------- k3: y[b,s] = sum_r alpha[b,r]*inp[r,b,s] + out_b ----------------
// 512 blocks (2/CU, 8 waves/CU), scalar coalesced loads, streaming.
__global__ __launch_bounds__(256) void k3_out(const float* __restrict__ inp,
        const float* __restrict__ alpha, const float* __restrict__ out_b,
        float* __restrict__ y)
{
    int g = blockIdx.x*256 + threadIdx.x;
    int b = g >> 14;                 // 64 blocks per batch -> b uniform per block
    int s = g & (HW-1);
    const float* al = alpha + b*NK;  // wave-uniform -> s_load
    float a = out_b[0];
    const float* base = inp + (size_t)b*NC*HW + s;
#pragma unroll
    for (int f=0; f<NF; ++f){
        const float* fb = base + (size_t)f*FSTRIDE;
#pragma unroll 8
        for (int c=0; c<NC; ++c)
            a = fmaf(al[f*NC + c], fb[(size_t)c*HW], a);
    }
    y[(size_t)b*HW + s] = a;
}

extern "C" void kernel_launch(void* const* d_in, const int* in_sizes, int n_in,
                              void* d_out, int out_size, void* d_ws, size_t ws_size,
                              hipStream_t stream)
{
    const float* inp      = (const float*)d_in[0];
    const float* origin_w = (const float*)d_in[1];
    const float* origin_b = (const float*)d_in[2];
    const float* out_w    = (const float*)d_in[3];
    const float* out_b    = (const float*)d_in[4];
    float* y  = (float*)d_out;
    float* ws = (float*)d_ws;

    float* EN    = ws;                              // 4096 floats
    float* alpha = ws + EN_FLOATS;                  // 2560 floats
    float* Wt    = ws + EN_FLOATS + ALPHA_FLOATS;   // 20480 floats

    hipMemsetAsync(EN, 0, EN_FLOATS*sizeof(float), stream);
    k0_wt   <<<(NC*NK + 255)/256, 256, 0, stream>>>(origin_w, Wt);
    k1_fused<<<512, 256, 0, stream>>>(inp, Wt, origin_b, EN);
    k2_coef <<<1, NB*NC, 0, stream>>>(EN, out_w, alpha);
    k3_out  <<<512, 256, 0, stream>>>(inp, alpha, out_b, y);
}

// Round 5
// 388.149 us; speedup vs baseline: 1.2947x; 1.2947x over previous
//
#include <hip/hip_runtime.h>
#include <math.h>

// Problem constants
#define NF 5
#define NB 8
#define NC 64
#define HW 16384
#define NK 320               // NF*NC
#define FSTRIDE (NB*NC*HW)   // elements per frame = 8388608

// ws layout (floats)
#define EN_FLOATS    (NB*NC*8)   // 4096: per (b,c): E0..E3, N0..N3
#define ALPHA_FLOATS (NB*NK)     // 2560

#define OST 68               // padded LDS row stride (words): breaks 16-row bank aliasing

// ---------------- k0: transpose origin_w [64][320] -> Wt [320][64] ----------------
__global__ void k0_wt(const float* __restrict__ W, float* __restrict__ Wt){
    int idx = blockIdx.x*256 + threadIdx.x;
    if (idx < NC*NK){
        int c = idx / NK;
        int k = idx - c*NK;
        Wt[k*NC + c] = W[idx];
    }
}

// ---------------- k1: fused GEMM + E/N, low-register design ----------------
// Block = 256 thr, grid = 2048 (b = blk>>8, s0 = (blk&255)*64). LDS 17.4 KB
// -> 8 blocks/CU, 32 waves/CU. Per-thread state ~35 VGPRs: BELOW the
// backend's 64-VGPR/8-wave occupancy target, so nothing gets spilled
// (rounds 2-4: 64 accumulators/thread made the occupancy heuristic spill
// 32-44 MB of scratch regardless of alloca form or launch_bounds).
//
// Phase A: thread (cg=tid>>5, sg=tid&31) computes o[c0..c0+7][s0+2sg..+1]:
//   8 float2 accs. W_f staged in LDS per frame; per k: two ds_read_b128
//   BROADCASTS (half-wave reads one address) + one coalesced float2 X load
//   + 16 FMAs. X is read once from HBM (all 4 waves share via L1).
// Phase B: thread = (c=tid>>2, i=tid&3). o dumped to LDS (stride 68),
//   E/N summed over the 64-wide s-window from rows this block already
//   fetched (L1/L2-hot), one atomicAdd pair per thread.
__global__ __launch_bounds__(256) void k1_fused(
    const float* __restrict__ inp, const float* __restrict__ Wt,
    const float* __restrict__ bias, float* __restrict__ EN)
{
    __shared__ float S[64*OST];     // 17408 B: W panel, then o tile

    const int tid = threadIdx.x;
    const int cg  = tid >> 5;       // 0..7: channel group
    const int sg  = tid & 31;       // 0..31: spatial pair
    const int c0  = cg << 3;
    const int b   = blockIdx.x >> 8;
    const int s0  = (blockIdx.x & 255) << 6;

    // ---- Phase A ----
    float2 a0,a1,a2,a3,a4,a5,a6,a7;
    {
        float4 b0 = *reinterpret_cast<const float4*>(bias + c0);
        float4 b1 = *reinterpret_cast<const float4*>(bias + c0 + 4);
        a0 = make_float2(b0.x,b0.x); a1 = make_float2(b0.y,b0.y);
        a2 = make_float2(b0.z,b0.z); a3 = make_float2(b0.w,b0.w);
        a4 = make_float2(b1.x,b1.x); a5 = make_float2(b1.y,b1.y);
        a6 = make_float2(b1.z,b1.z); a7 = make_float2(b1.w,b1.w);
    }

    const int wrow = tid >> 2;          // staging: row 0..63
    const int wcol = (tid & 3) << 4;    // col 0/16/32/48

#pragma unroll 1
    for (int f=0; f<NF; ++f){
        __syncthreads();                // prev frame's W reads done
        {   // stage W_f[64][64] -> S (stride OST); coalesced global, b128 LDS
            const float* wg = Wt + f*(NC*NC) + wrow*NC + wcol;
            float4 w0 = *reinterpret_cast<const float4*>(wg);
            float4 w1 = *reinterpret_cast<const float4*>(wg + 4);
            float4 w2 = *reinterpret_cast<const float4*>(wg + 8);
            float4 w3 = *reinterpret_cast<const float4*>(wg + 12);
            float* wd = S + wrow*OST + wcol;
            *reinterpret_cast<float4*>(wd)      = w0;
            *reinterpret_cast<float4*>(wd + 4)  = w1;
            *reinterpret_cast<float4*>(wd + 8)  = w2;
            *reinterpret_cast<float4*>(wd + 12) = w3;
        }
        __syncthreads();

        const float* xp = inp + (size_t)(f*NB + b)*NC*HW + s0 + (sg << 1);
#pragma unroll 4
        for (int k=0; k<64; ++k){
            float2 xv = *reinterpret_cast<const float2*>(xp);
            xp += HW;
            float4 wA = *reinterpret_cast<const float4*>(S + k*OST + c0);      // broadcast
            float4 wB = *reinterpret_cast<const float4*>(S + k*OST + c0 + 4);  // broadcast
            a0.x = fmaf(wA.x, xv.x, a0.x); a0.y = fmaf(wA.x, xv.y, a0.y);
            a1.x = fmaf(wA.y, xv.x, a1.x); a1.y = fmaf(wA.y, xv.y, a1.y);
            a2.x = fmaf(wA.z, xv.x, a2.x); a2.y = fmaf(wA.z, xv.y, a2.y);
            a3.x = fmaf(wA.w, xv.x, a3.x); a3.y = fmaf(wA.w, xv.y, a3.y);
            a4.x = fmaf(wB.x, xv.x, a4.x); a4.y = fmaf(wB.x, xv.y, a4.y);
            a5.x = fmaf(wB.y, xv.x, a5.x); a5.y = fmaf(wB.y, xv.y, a5.y);
            a6.x = fmaf(wB.z, xv.x, a6.x); a6.y = fmaf(wB.z, xv.y, a6.y);
            a7.x = fmaf(wB.w, xv.x, a7.x); a7.y = fmaf(wB.w, xv.y, a7.y);
        }
    }

    // ---- dump o to LDS: Ol[c][s], stride OST ----
    __syncthreads();                    // last W reads done before overwrite
    {
        float* od = S + (size_t)c0*OST + (sg << 1);
        *reinterpret_cast<float2*>(od + 0*OST) = a0;
        *reinterpret_cast<float2*>(od + 1*OST) = a1;
        *reinterpret_cast<float2*>(od + 2*OST) = a2;
        *reinterpret_cast<float2*>(od + 3*OST) = a3;
        *reinterpret_cast<float2*>(od + 4*OST) = a4;
        *reinterpret_cast<float2*>(od + 5*OST) = a5;
        *reinterpret_cast<float2*>(od + 6*OST) = a6;
        *reinterpret_cast<float2*>(od + 7*OST) = a7;
    }
    __syncthreads();

    // ---- Phase B: thread = (c, i) ----
    const int c  = tid >> 2;
    const int ii = tid & 3;
    const float* orow = S + c*OST;
    const float* x4r  = inp + (size_t)(4*NB + b)*NC*HW + (size_t)c*HW + s0;
    const float* xir  = inp + (size_t)(ii*NB + b)*NC*HW + (size_t)c*HW + s0;
    float e = 0.f, n = 0.f;
#pragma unroll 4
    for (int j=0; j<16; ++j){
        float4 ov = *reinterpret_cast<const float4*>(orow + 4*j);
        float4 x4 = *reinterpret_cast<const float4*>(x4r  + 4*j);
        float4 xi = *reinterpret_cast<const float4*>(xir  + 4*j);
        float d0 = x4.x - xi.x, d1 = x4.y - xi.y;
        float d2 = x4.z - xi.z, d3 = x4.w - xi.w;
        n = fmaf(d0,d0, fmaf(d1,d1, fmaf(d2,d2, fmaf(d3,d3, n))));
        e = fmaf(ov.x,d0, fmaf(ov.y,d1, fmaf(ov.z,d2, fmaf(ov.w,d3, e))));
    }
    float* enb = EN + ((size_t)b*NC + c)*8;
    atomicAdd(&enb[ii],     e);
    atomicAdd(&enb[4 + ii], n);
}

// ---------------- k2: finalize coef -> alpha ----------------
__global__ void k2_coef(const float* __restrict__ EN, const float* __restrict__ out_w,
                        float* __restrict__ alpha)
{
    int tid = threadIdx.x;          // 512 = NB*NC
    int b = tid >> 6, c = tid & 63;
    const float* e = EN + (b*NC + c)*8;
    float w1 = out_w[c], w2 = out_w[NC + c];
    float csum = 0.f;
#pragma unroll
    for (int i=0; i<4; ++i){
        float nc = fmaxf(sqrtf(e[4+i]), 1e-12f);
        float coef = e[i] / (nc*nc);
        alpha[b*NK + i*NC + c] = -w1*coef;
        csum += coef;
    }
    alpha[b*NK + 4*NC + c] = w1*csum + w2;
}

// ---------------- k3: y[b,s] = sum_r alpha[b,r]*inp[r,b,s] + out_b ----------------
// 256 blocks x 128 thr; thread owns 4 consecutive s via float4 loads
// (16B/lane = the measured-6.3TB/s access shape; round 2-4's 4B/lane walk
// ran at ~1 TB/s). alpha staged in LDS -> broadcast reads, no s_load gamble.
__global__ __launch_bounds__(128) void k3_out(const float* __restrict__ inp,
        const float* __restrict__ alpha, const float* __restrict__ out_b,
        float* __restrict__ y)
{
    __shared__ float Al[NK];
    const int tid = threadIdx.x;
    const int b   = blockIdx.x >> 5;          // 32 blocks per batch
    const int s0  = (blockIdx.x & 31) << 9;   // 512-wide window
    if (tid < 80)
        *reinterpret_cast<float4*>(&Al[tid*4]) =
            *reinterpret_cast<const float4*>(alpha + b*NK + tid*4);
    __syncthreads();

    const int s = s0 + tid*4;
    float bb = out_b[0];
    float4 acc = make_float4(bb, bb, bb, bb);
    const float* base = inp + (size_t)b*NC*HW + s;

#define K3FMA(XV, WS) \
    acc.x = fmaf(WS, XV.x, acc.x); acc.y = fmaf(WS, XV.y, acc.y); \
    acc.z = fmaf(WS, XV.z, acc.z); acc.w = fmaf(WS, XV.w, acc.w);

#pragma unroll 1
    for (int f=0; f<NF; ++f){
        const float* fb = base + (size_t)f*FSTRIDE;
#pragma unroll 1
        for (int cc=0; cc<8; ++cc){
            const float* rb = fb + (size_t)cc*8*HW;
            float4 x0 = *reinterpret_cast<const float4*>(rb + (size_t)0*HW);
            float4 x1 = *reinterpret_cast<const float4*>(rb + (size_t)1*HW);
            float4 x2 = *reinterpret_cast<const float4*>(rb + (size_t)2*HW);
            float4 x3 = *reinterpret_cast<const float4*>(rb + (size_t)3*HW);
            float4 x4 = *reinterpret_cast<const float4*>(rb + (size_t)4*HW);
            float4 x5 = *reinterpret_cast<const float4*>(rb + (size_t)5*HW);
            float4 x6 = *reinterpret_cast<const float4*>(rb + (size_t)6*HW);
            float4 x7 = *reinterpret_cast<const float4*>(rb + (size_t)7*HW);
            float4 w0 = *reinterpret_cast<const float4*>(&Al[f*NC + cc*8]);
            float4 w1 = *reinterpret_cast<const float4*>(&Al[f*NC + cc*8 + 4]);
            K3FMA(x0, w0.x) K3FMA(x1, w0.y) K3FMA(x2, w0.z) K3FMA(x3, w0.w)
            K3FMA(x4, w1.x) K3FMA(x5, w1.y) K3FMA(x6, w1.z) K3FMA(x7, w1.w)
        }
    }
#undef K3FMA
    *reinterpret_cast<float4*>(y + (size_t)b*HW + s) = acc;
}

extern "C" void kernel_launch(void* const* d_in, const int* in_sizes, int n_in,
                              void* d_out, int out_size, void* d_ws, size_t ws_size,
                              hipStream_t stream)
{
    const float* inp      = (const float*)d_in[0];
    const float* origin_w = (const float*)d_in[1];
    const float* origin_b = (const float*)d_in[2];
    const float* out_w    = (const float*)d_in[3];
    const float* out_b    = (const float*)d_in[4];
    float* y  = (float*)d_out;
    float* ws = (float*)d_ws;

    float* EN    = ws;                              // 4096 floats
    float* alpha = ws + EN_FLOATS;                  // 2560 floats
    float* Wt    = ws + EN_FLOATS + ALPHA_FLOATS;   // 20480 floats

    hipMemsetAsync(EN, 0, EN_FLOATS*sizeof(float), stream);
    k0_wt   <<<(NC*NK + 255)/256, 256, 0, stream>>>(origin_w, Wt);
    k1_fused<<<2048, 256, 0, stream>>>(inp, Wt, origin_b, EN);
    k2_coef <<<1, NB*NC, 0, stream>>>(EN, out_w, alpha);
    k3_out  <<<256, 128, 0, stream>>>(inp, alpha, out_b, y);
}